// Round 3
// baseline (56.853 us; speedup 1.0000x reference)
//
#include <hip/hip_runtime.h>

#define B_N 8
#define C_N 8
#define F_N 257
#define T_N 2000
#define EPSF 1e-6f

#define FCH 32            // F chunks
#define FPC 9             // ceil(257/32) rows per chunk

typedef float f32x4 __attribute__((ext_vector_type(4)));

// ---- Kernel A: partial |X[b,rc,f,t]| sums over an F-chunk. 256 blocks. ----
__global__ __launch_bounds__(512) void partial_mean_kernel(
    const float* __restrict__ X, const int* __restrict__ ref_ch,
    f32x4* __restrict__ part4 /* [B][FCH][T/4] */)
{
    const int b   = blockIdx.x;
    const int c   = blockIdx.y;
    const int tid = threadIdx.x;
    if (tid >= T_N / 4) return;

    const int rc = ref_ch[0];
    const f32x4* Xb4 =
        (const f32x4*)(X + ((size_t)(b * C_N + rc)) * (size_t)F_N * T_N);

    const int f0 = c * FPC;
    const int f1 = (f0 + FPC < F_N) ? (f0 + FPC) : F_N;

    f32x4 acc = {0.f, 0.f, 0.f, 0.f};
    for (int f = f0; f < f1; ++f) {
        f32x4 v = Xb4[f * (T_N / 4) + tid];
        acc.x += fabsf(v.x); acc.y += fabsf(v.y);
        acc.z += fabsf(v.z); acc.w += fabsf(v.w);
    }
    part4[(b * FCH + c) * (T_N / 4) + tid] = acc;
}

// ---- Kernel B: reduce partials -> mean, parallel affine scan ->
//      inv[b][t] = 1/(mu_t + eps). One block per batch. ----
__global__ __launch_bounds__(512) void scan_kernel(
    const f32x4* __restrict__ part4,
    f32x4* __restrict__ inv4 /* [B][T/4] */)
{
    __shared__ float s_mean[T_N];
    __shared__ float s_wA[8];
    __shared__ float s_wB[8];
    const float ALPHA = (float)(191.0 / 193.0);

    const int b   = blockIdx.x;
    const int tid = threadIdx.x;

    if (tid < T_N / 4) {
        f32x4 s = {0.f, 0.f, 0.f, 0.f};
        #pragma unroll
        for (int c = 0; c < FCH; ++c)
            s += part4[(b * FCH + c) * (T_N / 4) + tid];
        const int t = tid * 4;
        const float inv_f = 1.f / (float)F_N;
        s_mean[t + 0] = s.x * inv_f;
        s_mean[t + 1] = s.y * inv_f;
        s_mean[t + 2] = s.z * inv_f;
        s_mean[t + 3] = s.w * inv_f;
    }
    __syncthreads();

    // Affine scan: transform (A,B): mu -> A*mu + B. Local composite of 4 t's.
    float A = 1.f, Bv = 0.f;
    const int tbase = tid * 4;
    #pragma unroll
    for (int k = 0; k < 4; ++k) {
        const int t = tbase + k;
        if (t < T_N) {
            const float tf = (float)t;
            const float a = fminf((tf - 1.f) / (tf + 1.f), ALPHA);
            const float x = s_mean[t];
            Bv = a * Bv + (1.f - a) * x;
            A  = a * A;
        }
    }

    // Inclusive Hillis-Steele scan across the 64-lane wave.
    const int lane = tid & 63;
    #pragma unroll
    for (int d = 1; d < 64; d <<= 1) {
        const float pA = __shfl_up(A, d);
        const float pB = __shfl_up(Bv, d);
        if (lane >= d) {
            Bv = A * pB + Bv;
            A  = A * pA;
        }
    }

    // Cross-wave (8 waves) exclusive composite via LDS.
    const int wid = tid >> 6;
    if (lane == 63) { s_wA[wid] = A; s_wB[wid] = Bv; }
    __syncthreads();
    if (tid == 0) {
        float cA = 1.f, cB = 0.f;
        #pragma unroll
        for (int w = 0; w < 8; ++w) {
            const float nA = s_wA[w] * cA;
            const float nB = s_wA[w] * cB + s_wB[w];
            s_wA[w] = cA; s_wB[w] = cB;
            cA = nA; cB = nB;
        }
    }
    __syncthreads();

    float eA = __shfl_up(A, 1);
    float eB = __shfl_up(Bv, 1);
    if (lane == 0) { eA = 1.f; eB = 0.f; }
    float mu = eA * s_wB[wid] + eB;   // applied to mu0 = 0

    if (tid < T_N / 4) {
        f32x4 r;
        #pragma unroll
        for (int k = 0; k < 4; ++k) {
            const int t = tbase + k;
            const float tf = (float)t;
            const float a = fminf((tf - 1.f) / (tf + 1.f), ALPHA);
            const float x = s_mean[t];
            mu = a * mu + (1.f - a) * x;
            r[k] = 1.f / (mu + EPSF);
        }
        inv4[b * (T_N / 4) + tid] = r;
    }
}

// ---- Kernel C: streaming out = X * inv[b,t]. NT loads/stores on the
//      no-reuse streams; inv stays cached. grid = (chunks, B). ----
__global__ __launch_bounds__(256) void norm_kernel(
    const f32x4* __restrict__ X4,
    const f32x4* __restrict__ inv4,
    f32x4* __restrict__ out4)
{
    const int PER_B = C_N * F_N * T_N / 4;         // 1,028,000 float4
    const int i  = blockIdx.x * 256 + threadIdx.x; // index within batch
    if (i >= PER_B) return;
    const int b  = blockIdx.y;
    const int tq = i % (T_N / 4);

    const size_t g = (size_t)b * PER_B + i;
    const f32x4 iv = inv4[b * (T_N / 4) + tq];
    const f32x4 x  = __builtin_nontemporal_load(X4 + g);
    __builtin_nontemporal_store(x * iv, out4 + g);
}

extern "C" void kernel_launch(void* const* d_in, const int* in_sizes, int n_in,
                              void* d_out, int out_size, void* d_ws, size_t ws_size,
                              hipStream_t stream) {
    const float* X  = (const float*)d_in[0];
    const int*   rc = (const int*)d_in[1];

    float* inv  = (float*)d_ws;                    // B*T floats      = 64 KB
    float* part = (float*)d_ws + B_N * T_N;        // B*FCH*T floats  = 2 MB

    dim3 gA(B_N, FCH);
    partial_mean_kernel<<<gA, 512, 0, stream>>>(X, rc, (f32x4*)part);

    scan_kernel<<<B_N, 512, 0, stream>>>((const f32x4*)part, (f32x4*)inv);

    const int PER_B = C_N * F_N * T_N / 4;
    dim3 gC((PER_B + 255) / 256, B_N);
    norm_kernel<<<gC, 256, 0, stream>>>(
        (const f32x4*)X, (const f32x4*)inv, (f32x4*)d_out);
}

// Round 4
// 56.851 us; speedup vs baseline: 1.0000x; 1.0000x over previous
//
#include <hip/hip_runtime.h>

#define B_N 8
#define C_N 8
#define F_N 257
#define T_N 2000
#define EPSF 1e-6f

#define FCH 32            // F chunks
#define FPC 9             // ceil(257/32) rows per chunk

typedef float f32x4 __attribute__((ext_vector_type(4)));

// ---- Kernel A: partial |X[b,rc,f,t]| sums over an F-chunk. 256 blocks. ----
__global__ __launch_bounds__(512) void partial_mean_kernel(
    const float* __restrict__ X, const int* __restrict__ ref_ch,
    f32x4* __restrict__ part4 /* [B][FCH][T/4] */)
{
    const int b   = blockIdx.x;
    const int c   = blockIdx.y;
    const int tid = threadIdx.x;
    if (tid >= T_N / 4) return;

    const int rc = ref_ch[0];
    const f32x4* Xb4 =
        (const f32x4*)(X + ((size_t)(b * C_N + rc)) * (size_t)F_N * T_N);

    const int f0 = c * FPC;
    const int f1 = (f0 + FPC < F_N) ? (f0 + FPC) : F_N;

    f32x4 acc = {0.f, 0.f, 0.f, 0.f};
    for (int f = f0; f < f1; ++f) {
        f32x4 v = Xb4[f * (T_N / 4) + tid];
        acc.x += fabsf(v.x); acc.y += fabsf(v.y);
        acc.z += fabsf(v.z); acc.w += fabsf(v.w);
    }
    part4[(b * FCH + c) * (T_N / 4) + tid] = acc;
}

// ---- Kernel B: reduce partials -> mean, parallel affine scan ->
//      inv[b][t] = 1/(mu_t + eps). One block per batch. ----
__global__ __launch_bounds__(512) void scan_kernel(
    const f32x4* __restrict__ part4,
    f32x4* __restrict__ inv4 /* [B][T/4] */)
{
    __shared__ float s_mean[T_N];
    __shared__ float s_wA[8];
    __shared__ float s_wB[8];
    const float ALPHA = (float)(191.0 / 193.0);

    const int b   = blockIdx.x;
    const int tid = threadIdx.x;

    if (tid < T_N / 4) {
        f32x4 s = {0.f, 0.f, 0.f, 0.f};
        #pragma unroll
        for (int c = 0; c < FCH; ++c)
            s += part4[(b * FCH + c) * (T_N / 4) + tid];
        const int t = tid * 4;
        const float inv_f = 1.f / (float)F_N;
        s_mean[t + 0] = s.x * inv_f;
        s_mean[t + 1] = s.y * inv_f;
        s_mean[t + 2] = s.z * inv_f;
        s_mean[t + 3] = s.w * inv_f;
    }
    __syncthreads();

    // Affine scan: transform (A,B): mu -> A*mu + B. Local composite of 4 t's.
    float A = 1.f, Bv = 0.f;
    const int tbase = tid * 4;
    #pragma unroll
    for (int k = 0; k < 4; ++k) {
        const int t = tbase + k;
        if (t < T_N) {
            const float tf = (float)t;
            const float a = fminf((tf - 1.f) / (tf + 1.f), ALPHA);
            const float x = s_mean[t];
            Bv = a * Bv + (1.f - a) * x;
            A  = a * A;
        }
    }

    // Inclusive Hillis-Steele scan across the 64-lane wave.
    const int lane = tid & 63;
    #pragma unroll
    for (int d = 1; d < 64; d <<= 1) {
        const float pA = __shfl_up(A, d);
        const float pB = __shfl_up(Bv, d);
        if (lane >= d) {
            Bv = A * pB + Bv;
            A  = A * pA;
        }
    }

    // Cross-wave (8 waves) exclusive composite via LDS.
    const int wid = tid >> 6;
    if (lane == 63) { s_wA[wid] = A; s_wB[wid] = Bv; }
    __syncthreads();
    if (tid == 0) {
        float cA = 1.f, cB = 0.f;
        #pragma unroll
        for (int w = 0; w < 8; ++w) {
            const float nA = s_wA[w] * cA;
            const float nB = s_wA[w] * cB + s_wB[w];
            s_wA[w] = cA; s_wB[w] = cB;
            cA = nA; cB = nB;
        }
    }
    __syncthreads();

    float eA = __shfl_up(A, 1);
    float eB = __shfl_up(Bv, 1);
    if (lane == 0) { eA = 1.f; eB = 0.f; }
    float mu = eA * s_wB[wid] + eB;   // applied to mu0 = 0

    if (tid < T_N / 4) {
        f32x4 r;
        #pragma unroll
        for (int k = 0; k < 4; ++k) {
            const int t = tbase + k;
            const float tf = (float)t;
            const float a = fminf((tf - 1.f) / (tf + 1.f), ALPHA);
            const float x = s_mean[t];
            mu = a * mu + (1.f - a) * x;
            r[k] = 1.f / (mu + EPSF);
        }
        inv4[b * (T_N / 4) + tid] = r;
    }
}

// ---- Kernel C: streaming out = X * inv[b,t]. NT loads/stores on the
//      no-reuse streams; inv stays cached. grid = (chunks, B). ----
__global__ __launch_bounds__(256) void norm_kernel(
    const f32x4* __restrict__ X4,
    const f32x4* __restrict__ inv4,
    f32x4* __restrict__ out4)
{
    const int PER_B = C_N * F_N * T_N / 4;         // 1,028,000 float4
    const int i  = blockIdx.x * 256 + threadIdx.x; // index within batch
    if (i >= PER_B) return;
    const int b  = blockIdx.y;
    const int tq = i % (T_N / 4);

    const size_t g = (size_t)b * PER_B + i;
    const f32x4 iv = inv4[b * (T_N / 4) + tq];
    const f32x4 x  = __builtin_nontemporal_load(X4 + g);
    __builtin_nontemporal_store(x * iv, out4 + g);
}

extern "C" void kernel_launch(void* const* d_in, const int* in_sizes, int n_in,
                              void* d_out, int out_size, void* d_ws, size_t ws_size,
                              hipStream_t stream) {
    const float* X  = (const float*)d_in[0];
    const int*   rc = (const int*)d_in[1];

    float* inv  = (float*)d_ws;                    // B*T floats      = 64 KB
    float* part = (float*)d_ws + B_N * T_N;        // B*FCH*T floats  = 2 MB

    dim3 gA(B_N, FCH);
    partial_mean_kernel<<<gA, 512, 0, stream>>>(X, rc, (f32x4*)part);

    scan_kernel<<<B_N, 512, 0, stream>>>((const f32x4*)part, (f32x4*)inv);

    const int PER_B = C_N * F_N * T_N / 4;
    dim3 gC((PER_B + 255) / 256, B_N);
    norm_kernel<<<gC, 256, 0, stream>>>(
        (const f32x4*)X, (const f32x4*)inv, (f32x4*)d_out);
}